// Round 1
// baseline (1144.684 us; speedup 1.0000x reference)
//
#include <hip/hip_runtime.h>
#include <hip/hip_bf16.h>

// SimVQ forward for MI355X (gfx950).
// z:[32768,512] f32, embedding:[8192,512], proj weights 512x512.
// Outputs concatenated: quantized[16777216] f32, vq_loss[1] f32, idx[32768] (as f32).
//
// idx = argmax_n z_proj . c_n  (z-normalization is a positive per-row scale -> argmin-invariant)
//     = argmax_n  z . (Wz^T c_n) + bz . c_n
// All GEMMs use split-bf16 (hi+lo) MFMA: x = hi + lo, x*y ~= hi*hi + hi*lo + lo*hi.
// R3: loss via per-block partials. R4 FAILED: 64x128 wave tile spilled (scratch).
// R5: qc/e GEMMs converted to split-bf16 MFMA.
// R6: k_scores rewritten as 256x256-tile / BK=32 / 8-wave / 128KB-dbuf-LDS
//     8-phase schedule (T3+T4 counted vmcnt + T5 setprio). Interleaved wave
//     tiling (wave rows = {wm*64..} u {128+wm*64..}) so each phase consumes
//     exactly one freshly-landed staged half-tile; steady-state waits are
//     vmcnt(4) (never 0) so 4-8 global_load_lds stay in flight across every
//     barrier. Raw s_barrier (no implicit drain) + asm waitcnts.

#define NQ    32768
#define NEMB  8192
#define DD    512

typedef __attribute__((ext_vector_type(8))) short bf16x8;
typedef __attribute__((ext_vector_type(4))) float f32x4;

__device__ __forceinline__ unsigned short f2bf_rne(float f) {
    unsigned u = __float_as_uint(f);
    unsigned r = u + 0x7FFFu + ((u >> 16) & 1u);
    return (unsigned short)(r >> 16);
}
__device__ __forceinline__ float bf2f(unsigned short b) {
    return __uint_as_float(((unsigned)b) << 16);
}

__device__ __forceinline__ void gload16(const void* g, void* l) {
    __builtin_amdgcn_global_load_lds(
        (const __attribute__((address_space(1))) unsigned int*)g,
        (__attribute__((address_space(3))) unsigned int*)l, 16, 0, 0);
}

// ---------------- generic fp32 -> bf16 hi/lo split ---------------------------
__global__ __launch_bounds__(256) void k_split(const float* __restrict__ src,
                                               unsigned short* __restrict__ hi,
                                               unsigned short* __restrict__ lo,
                                               int n4) {
    const float4* s4 = (const float4*)src;
    ushort4* h4 = (ushort4*)hi;
    ushort4* l4 = (ushort4*)lo;
    for (int i = blockIdx.x * blockDim.x + threadIdx.x; i < n4; i += gridDim.x * blockDim.x) {
        float4 v = s4[i];
        ushort4 h, l;
        h.x = f2bf_rne(v.x); l.x = f2bf_rne(v.x - bf2f(h.x));
        h.y = f2bf_rne(v.y); l.y = f2bf_rne(v.y - bf2f(h.y));
        h.z = f2bf_rne(v.z); l.z = f2bf_rne(v.z - bf2f(h.z));
        h.w = f2bf_rne(v.w); l.w = f2bf_rne(v.w - bf2f(h.w));
        h4[i] = h;
        l4[i] = l;
    }
}

// ---------------- transpose + split: T[k][d] = W[d][k] -----------------------
__global__ __launch_bounds__(256) void k_wtsplit(const float* __restrict__ W,
                                                 unsigned short* __restrict__ thi,
                                                 unsigned short* __restrict__ tlo) {
    __shared__ float t[32][33];
    const int bx = blockIdx.x * 32;  // output row block (k)
    const int by = blockIdx.y * 32;  // output col block (d)
    const int c = threadIdx.x & 31, r0 = threadIdx.x >> 5;
    for (int i = 0; i < 4; ++i) {
        int r = r0 + i * 8;
        t[r][c] = W[(size_t)(by + r) * DD + bx + c];
    }
    __syncthreads();
    for (int i = 0; i < 4; ++i) {
        int r = r0 + i * 8;
        float v = t[c][r];  // = W[by+c][bx+r]
        unsigned short h = f2bf_rne(v);
        thi[(size_t)(bx + r) * DD + by + c] = h;
        tlo[(size_t)(bx + r) * DD + by + c] = f2bf_rne(v - bf2f(h));
    }
}

// ---------------- MFMA GEMM core (128x128 tile, small GEMMs) -----------------
// XOR bank swizzle: k-group kg of row m stored at kg^((m>>1)&3) (verified R2:
// 0 bank conflicts; staging stays fully coalesced under global_load_lds).

// Kernel: qc = emb @ Wp^T + bp  (writes fp32 qc AND its bf16 hi/lo split)
__global__ __launch_bounds__(256, 3) void k_qc_mfma(const unsigned short* __restrict__ Ah,
                                                    const unsigned short* __restrict__ Al,
                                                    const unsigned short* __restrict__ Bh,
                                                    const unsigned short* __restrict__ Bl,
                                                    const float* __restrict__ bias,
                                                    float* __restrict__ qc,
                                                    unsigned short* __restrict__ qhi,
                                                    unsigned short* __restrict__ qlo) {
    __shared__ unsigned short sAh[128 * 32];
    __shared__ unsigned short sAl[128 * 32];
    __shared__ unsigned short sBh[128 * 32];
    __shared__ unsigned short sBl[128 * 32];

    const int t    = threadIdx.x;
    const int lane = t & 63;
    const int wave = t >> 6;
    const int wm   = wave >> 1;
    const int wn   = wave & 1;
    const int m0   = blockIdx.y * 128;
    const int n0   = blockIdx.x * 128;

    f32x4 acc[4][4];
    for (int i = 0; i < 4; ++i)
        for (int j = 0; j < 4; ++j) acc[i][j] = (f32x4){0.f, 0.f, 0.f, 0.f};

    const int koff = (((lane >> 4) ^ ((lane >> 1) & 3)) << 3);

    for (int kb = 0; kb < DD; kb += 32) {
        for (int r = 0; r < 2; ++r) {
            const int cbase = r * 256 + wave * 64;
            const int c = cbase + lane;
            const int m = c >> 2;
            const int kg = (c & 3) ^ ((m >> 1) & 3);
            const size_t ga = (size_t)(m0 + m) * DD + kb + kg * 8;
            const size_t gb = (size_t)(n0 + m) * DD + kb + kg * 8;
            gload16(Ah + ga, &sAh[cbase * 8]);
            gload16(Al + ga, &sAl[cbase * 8]);
            gload16(Bh + gb, &sBh[cbase * 8]);
            gload16(Bl + gb, &sBl[cbase * 8]);
        }
        __syncthreads();

        bf16x8 afh[4], afl[4], bfh[4], bfl[4];
        const int ar = wm * 64 + (lane & 15);
        const int br = wn * 64 + (lane & 15);
        for (int i = 0; i < 4; ++i) {
            afh[i] = *(const bf16x8*)&sAh[(ar + i * 16) * 32 + koff];
            afl[i] = *(const bf16x8*)&sAl[(ar + i * 16) * 32 + koff];
            bfh[i] = *(const bf16x8*)&sBh[(br + i * 16) * 32 + koff];
            bfl[i] = *(const bf16x8*)&sBl[(br + i * 16) * 32 + koff];
        }
        for (int i = 0; i < 4; ++i)
            for (int j = 0; j < 4; ++j) {
                acc[i][j] = __builtin_amdgcn_mfma_f32_16x16x32_bf16(afh[i], bfh[j], acc[i][j], 0, 0, 0);
                acc[i][j] = __builtin_amdgcn_mfma_f32_16x16x32_bf16(afh[i], bfl[j], acc[i][j], 0, 0, 0);
                acc[i][j] = __builtin_amdgcn_mfma_f32_16x16x32_bf16(afl[i], bfh[j], acc[i][j], 0, 0, 0);
            }
        __syncthreads();
    }

    // epilogue: C/D layout col=lane&15, row=(lane>>4)*4+reg
    const int colb = lane & 15;
    const int g    = lane >> 4;
    float bcol[4];
    for (int tn = 0; tn < 4; ++tn) bcol[tn] = bias[n0 + wn * 64 + tn * 16 + colb];
    for (int tm = 0; tm < 4; ++tm) {
        for (int reg = 0; reg < 4; ++reg) {
            int row = m0 + wm * 64 + tm * 16 + g * 4 + reg;
            for (int tn = 0; tn < 4; ++tn) {
                int col = n0 + wn * 64 + tn * 16 + colb;
                float v = acc[tm][tn][reg] + bcol[tn];
                size_t o = (size_t)row * DD + col;
                qc[o] = v;
                unsigned short h = f2bf_rne(v);
                qhi[o] = h;
                qlo[o] = f2bf_rne(v - bf2f(h));
            }
        }
    }
}

// Kernel: e = rnorm .* (qc @ Wz)  via transposed-split Wz; writes bf16 hi/lo.
__global__ __launch_bounds__(256, 3) void k_e_mfma(const unsigned short* __restrict__ Ah,
                                                   const unsigned short* __restrict__ Al,
                                                   const unsigned short* __restrict__ Bh,
                                                   const unsigned short* __restrict__ Bl,
                                                   const float* __restrict__ rnorm,
                                                   unsigned short* __restrict__ ehi,
                                                   unsigned short* __restrict__ elo) {
    __shared__ unsigned short sAh[128 * 32];
    __shared__ unsigned short sAl[128 * 32];
    __shared__ unsigned short sBh[128 * 32];
    __shared__ unsigned short sBl[128 * 32];

    const int t    = threadIdx.x;
    const int lane = t & 63;
    const int wave = t >> 6;
    const int wm   = wave >> 1;
    const int wn   = wave & 1;
    const int m0   = blockIdx.y * 128;
    const int n0   = blockIdx.x * 128;

    f32x4 acc[4][4];
    for (int i = 0; i < 4; ++i)
        for (int j = 0; j < 4; ++j) acc[i][j] = (f32x4){0.f, 0.f, 0.f, 0.f};

    const int koff = (((lane >> 4) ^ ((lane >> 1) & 3)) << 3);

    for (int kb = 0; kb < DD; kb += 32) {
        for (int r = 0; r < 2; ++r) {
            const int cbase = r * 256 + wave * 64;
            const int c = cbase + lane;
            const int m = c >> 2;
            const int kg = (c & 3) ^ ((m >> 1) & 3);
            const size_t ga = (size_t)(m0 + m) * DD + kb + kg * 8;
            const size_t gb = (size_t)(n0 + m) * DD + kb + kg * 8;
            gload16(Ah + ga, &sAh[cbase * 8]);
            gload16(Al + ga, &sAl[cbase * 8]);
            gload16(Bh + gb, &sBh[cbase * 8]);
            gload16(Bl + gb, &sBl[cbase * 8]);
        }
        __syncthreads();

        bf16x8 afh[4], afl[4], bfh[4], bfl[4];
        const int ar = wm * 64 + (lane & 15);
        const int br = wn * 64 + (lane & 15);
        for (int i = 0; i < 4; ++i) {
            afh[i] = *(const bf16x8*)&sAh[(ar + i * 16) * 32 + koff];
            afl[i] = *(const bf16x8*)&sAl[(ar + i * 16) * 32 + koff];
            bfh[i] = *(const bf16x8*)&sBh[(br + i * 16) * 32 + koff];
            bfl[i] = *(const bf16x8*)&sBl[(br + i * 16) * 32 + koff];
        }
        for (int i = 0; i < 4; ++i)
            for (int j = 0; j < 4; ++j) {
                acc[i][j] = __builtin_amdgcn_mfma_f32_16x16x32_bf16(afh[i], bfh[j], acc[i][j], 0, 0, 0);
                acc[i][j] = __builtin_amdgcn_mfma_f32_16x16x32_bf16(afh[i], bfl[j], acc[i][j], 0, 0, 0);
                acc[i][j] = __builtin_amdgcn_mfma_f32_16x16x32_bf16(afl[i], bfh[j], acc[i][j], 0, 0, 0);
            }
        __syncthreads();
    }

    const int colb = lane & 15;
    const int g    = lane >> 4;
    for (int tm = 0; tm < 4; ++tm) {
        const int rbase = m0 + wm * 64 + tm * 16 + g * 4;
        float4 rn4 = *(const float4*)&rnorm[rbase];
        const float rnv[4] = {rn4.x, rn4.y, rn4.z, rn4.w};
        for (int reg = 0; reg < 4; ++reg) {
            int row = rbase + reg;
            for (int tn = 0; tn < 4; ++tn) {
                int col = n0 + wn * 64 + tn * 16 + colb;
                float v = acc[tm][tn][reg] * rnv[reg];
                size_t o = (size_t)row * DD + col;
                unsigned short h = f2bf_rne(v);
                ehi[o] = h;
                elo[o] = f2bf_rne(v - bf2f(h));
            }
        }
    }
}

// ---------------- per-row 1/norm and t_n numerator ---------------------------
__global__ __launch_bounds__(256) void k_norm(const float* __restrict__ qc,
                                              const float* __restrict__ bz,
                                              float* __restrict__ rnorm,
                                              float* __restrict__ tvec) {
    const int n = blockIdx.x;
    const int t = threadIdx.x;
    float ss = 0.f, tb = 0.f;
    for (int d = t; d < DD; d += 256) {
        float v = qc[(size_t)n * DD + d];
        ss += v * v;
        tb += bz[d] * v;
    }
    for (int off = 32; off; off >>= 1) {
        ss += __shfl_down(ss, off);
        tb += __shfl_down(tb, off);
    }
    __shared__ float s1[4], s2[4];
    int wave = t >> 6, lane = t & 63;
    if (lane == 0) { s1[wave] = ss; s2[wave] = tb; }
    __syncthreads();
    if (t == 0) {
        ss = s1[0] + s1[1] + s1[2] + s1[3];
        tb = s2[0] + s2[1] + s2[2] + s2[3];
        float norm = sqrtf(ss);
        float rn = 1.f / fmaxf(norm, 1e-12f);
        rnorm[n] = rn;
        tvec[n] = tb * rn;  // bz . c_n (normalized)
    }
}

// ---------------- scores + fused argmax: 256x256 8-phase (R6) ----------------
// 8 waves (2m x 4n), interleaved wave tiling:
//   wave wm rows : {h*128 + wm*64 + 0..63 : h in 0,1}
//   wave wn cols : {g*128 + wn*32 + 0..31 : g in 0,1}
// Phase (h,g) consumes A-block-half h and B-block-half g only -> staged
// half-tiles can be waited on incrementally with counted vmcnt.
// Per K-tile stage order (2 gload_lds/phase): zh0,zl0 | eh0,el0 | eh1,el1 | zh1,zl1
// Steady-state waits before phases 1,2,3: vmcnt(4); none before phase 4.

#define VMW(n) asm volatile("s_waitcnt vmcnt(" #n ")" ::: "memory")
#define BARRIER_() do { asm volatile("" ::: "memory"); __builtin_amdgcn_s_barrier(); asm volatile("" ::: "memory"); } while (0)

__global__ __launch_bounds__(512, 2) void k_scores(const unsigned short* __restrict__ Ah,
                                                   const unsigned short* __restrict__ Al,
                                                   const unsigned short* __restrict__ Bh,
                                                   const unsigned short* __restrict__ Bl,
                                                   const float* __restrict__ tvec,
                                                   unsigned long long* __restrict__ table) {
    // 128 KB: 2 bufs x {Ah(0), Al(8192), Bh(16384), Bl(24576)} x 256 rows x 32 k
    __shared__ unsigned short lds[65536];

    const int tid  = threadIdx.x;
    const int lane = tid & 63;
    const int wave = tid >> 6;
    const int wm   = wave >> 2;  // 0..1
    const int wn   = wave & 3;   // 0..3
    const int m0   = blockIdx.y * 256;
    const int n0   = blockIdx.x * 256;
    const int lrow = lane & 15;
    const int koff = ((lane >> 4) ^ ((lane >> 1) & 3)) << 3;

    // staging: thread c covers row (half*128 + c>>2), k-group (c&3), source
    // pre-swizzled so linear gload_lds dest realizes the XOR bank swizzle.
    const int crow = tid >> 2;
    const int kgs  = ((tid & 3) ^ ((tid >> 3) & 3)) << 3;
    const unsigned short* zh_ = Ah + (size_t)(m0 + crow) * DD + kgs;
    const unsigned short* zl_ = Al + (size_t)(m0 + crow) * DD + kgs;
    const unsigned short* eh_ = Bh + (size_t)(n0 + crow) * DD + kgs;
    const unsigned short* el_ = Bl + (size_t)(n0 + crow) * DD + kgs;
    unsigned short* lw = &lds[wave * 512];  // wave-uniform dest base (HW adds lane*16B)

#define STAGE(P, U, KB, NBO, XOFF) \
    gload16((P) + (size_t)(U) * (128 * DD) + (KB), lw + (NBO) + (XOFF) + (U) * 4096)

    f32x4 acc[8][4];
#pragma unroll
    for (int i = 0; i < 8; ++i)
#pragma unroll
        for (int j = 0; j < 4; ++j) acc[i][j] = (f32x4){0.f, 0.f, 0.f, 0.f};

    bf16x8 afh[4], afl[4], bfh[2], bfl[2];

#define LOAD_A(BO, H)                                                          \
    _Pragma("unroll")                                                          \
    for (int s = 0; s < 4; ++s) {                                              \
        const int ro = (BO) + ((H) * 128 + wm * 64 + s * 16 + lrow) * 32 + koff; \
        afh[s] = *(const bf16x8*)&lds[ro];                                     \
        afl[s] = *(const bf16x8*)&lds[ro + 8192];                              \
    }

#define LOAD_B(BO, G)                                                          \
    _Pragma("unroll")                                                          \
    for (int u = 0; u < 2; ++u) {                                              \
        const int co = (BO) + 16384 + ((G) * 128 + wn * 32 + u * 16 + lrow) * 32 + koff; \
        bfh[u] = *(const bf16x8*)&lds[co];                                     \
        bfl[u] = *(const bf16x8*)&lds[co + 8192];                              \
    }

#define MFMA_Q(H, G)                                                           \
    __builtin_amdgcn_s_setprio(1);                                             \
    _Pragma("unroll")                                                          \
    for (int s = 0; s < 4; ++s) {                                              \
        _Pragma("unroll")                                                      \
        for (int u = 0; u < 2; ++u) {                                          \
            f32x4 a = acc[(H) * 4 + s][(G) * 2 + u];                           \
            a = __builtin_amdgcn_mfma_f32_16x16x32_bf16(afh[s], bfh[u], a, 0, 0, 0); \
            a = __builtin_amdgcn_mfma_f32_16x16x32_bf16(afh[s], bfl[u], a, 0, 0, 0); \
            a = __builtin_amdgcn_mfma_f32_16x16x32_bf16(afl[s], bfh[u], a, 0, 0, 0); \
            acc[(H) * 4 + s][(G) * 2 + u] = a;                                 \
        }                                                                      \
    }                                                                          \
    __builtin_amdgcn_s_setprio(0);

#define TILE(BO, NBO, KB, DOST, V1, V2, V3)                                    \
    {                                                                          \
        VMW(V1); BARRIER_();                                                   \
        LOAD_A(BO, 0) LOAD_B(BO, 0)                                            \
        if (DOST) { STAGE(zh_, 0, KB, NBO, 0); STAGE(zl_, 0, KB, NBO, 8192); } \
        MFMA_Q(0, 0)                                                           \
        VMW(V2); BARRIER_();                                                   \
        LOAD_B(BO, 1)                                                          \
        if (DOST) { STAGE(eh_, 0, KB, NBO, 16384); STAGE(el_, 0, KB, NBO, 24576); } \
        MFMA_Q(0, 1)                                                           \
        VMW(V3); BARRIER_();                                                   \
        LOAD_A(BO, 1) LOAD_B(BO, 0)                                            \
        if (DOST) { STAGE(eh_, 1, KB, NBO, 16384); STAGE(el_, 1, KB, NBO, 24576); } \
        MFMA_Q(1, 0)                                                           \
        BARRIER_();                                                            \
        LOAD_B(BO, 1)                                                          \
        if (DOST) { STAGE(zh_, 1, KB, NBO, 0); STAGE(zl_, 1, KB, NBO, 8192); } \
        MFMA_Q(1, 1)                                                           \
    }

    // prologue: stage K-tile 0 into buf0 in consumption order
    STAGE(zh_, 0, 0, 0, 0);
    STAGE(zl_, 0, 0, 0, 8192);
    STAGE(eh_, 0, 0, 0, 16384);
    STAGE(el_, 0, 0, 0, 24576);
    STAGE(eh_, 1, 0, 0, 16384);
    STAGE(el_, 1, 0, 0, 24576);
    STAGE(zh_, 1, 0, 0, 0);
    STAGE(zl_, 1, 0, 0, 8192);

    // tiles 0..13 (14 tiles), then tile 14 (stages tile 15), then tail tile 15
#pragma unroll 1
    for (int tp = 0; tp < 7; ++tp) {
        const int kb = tp * 64;
        TILE(0, 32768, kb + 32, 1, 4, 4, 4)
        TILE(32768, 0, kb + 64, 1, 4, 4, 4)
    }
    TILE(0, 32768, 480, 1, 4, 4, 4)
    TILE(32768, 0, 0, 0, 4, 2, 0)

    // ---------------- epilogue: fused argmax over the wave's 128x64 ----------
    const int colb = lrow;
    const int g4   = lane >> 4;
    float tc[4];
#pragma unroll
    for (int ni = 0; ni < 4; ++ni)
        tc[ni] = tvec[n0 + (ni >> 1) * 128 + wn * 32 + (ni & 1) * 16 + colb];

#pragma unroll
    for (int mi = 0; mi < 8; ++mi) {
#pragma unroll
        for (int reg = 0; reg < 4; ++reg) {
            float best = -3.4e38f;
            int   bn   = 0x7FFFFFFF;
#pragma unroll
            for (int ni = 0; ni < 4; ++ni) {
                float v = acc[mi][ni][reg] + tc[ni];
                int n = n0 + (ni >> 1) * 128 + wn * 32 + (ni & 1) * 16 + colb;
                if (v > best || (v == best && n < bn)) { best = v; bn = n; }
            }
            for (int off = 1; off < 16; off <<= 1) {
                float ov = __shfl_xor(best, off);
                int   on = __shfl_xor(bn, off);
                if (ov > best || (ov == best && on < bn)) { best = ov; bn = on; }
            }
            if (colb == 0) {
                unsigned u = __float_as_uint(best);
                unsigned key = (u & 0x80000000u) ? ~u : (u | 0x80000000u);
                unsigned long long packed =
                    ((unsigned long long)key << 32) |
                    (unsigned long long)(0xFFFFFFFFu - (unsigned)bn);
                int q = m0 + (mi >> 2) * 128 + wm * 64 + (mi & 3) * 16 + g4 * 4 + reg;
                atomicMax(&table[q], packed);
            }
        }
    }
#undef STAGE
#undef LOAD_A
#undef LOAD_B
#undef MFMA_Q
#undef TILE
}

// ---------------- gather quantized, per-block loss partial, idx --------------
__global__ __launch_bounds__(128) void k_gather(const unsigned long long* __restrict__ table,
                                                const float* __restrict__ qc,
                                                const float* __restrict__ z,
                                                float* __restrict__ outq,
                                                float* __restrict__ partials,
                                                float* __restrict__ outidx) {
    const int q = blockIdx.x;
    const int t = threadIdx.x;  // 128 threads, one float4 each
    unsigned long long p = table[q];
    const int idx = (int)(0xFFFFFFFFu - (unsigned)(p & 0xFFFFFFFFull));
    const float4* src = (const float4*)(qc + (size_t)idx * DD);
    const float4* zs  = (const float4*)(z + (size_t)q * DD);
    float4* dst = (float4*)(outq + (size_t)q * DD);
    float4 a = src[t], b = zs[t];
    dst[t] = a;
    float dx = a.x - b.x, dy = a.y - b.y, dz = a.z - b.z, dw = a.w - b.w;
    float ss = dx * dx + dy * dy + dz * dz + dw * dw;
    for (int off = 32; off; off >>= 1) ss += __shfl_down(ss, off);
    __shared__ float sbuf[2];
    if ((t & 63) == 0) sbuf[t >> 6] = ss;
    __syncthreads();
    if (t == 0) {
        partials[q] = sbuf[0] + sbuf[1];
        outidx[q] = (float)idx;
    }
}

// ---------------- final loss reduction ---------------------------------------
__global__ __launch_bounds__(1024) void k_loss(const float* __restrict__ partials,
                                               float* __restrict__ loss) {
    const int t = threadIdx.x;  // single block of 1024
    float s = 0.f;
    for (int i = t; i < NQ; i += 1024) s += partials[i];
    for (int off = 32; off; off >>= 1) s += __shfl_down(s, off);
    __shared__ float sbuf[16];
    if ((t & 63) == 0) sbuf[t >> 6] = s;
    __syncthreads();
    if (t == 0) {
        float tot = 0.f;
        for (int w = 0; w < 16; ++w) tot += sbuf[w];
        // vq_loss = (1 + beta) * mean((quantized - z)^2), beta = 0.25
        *loss = tot * (1.25f / 16777216.0f);
    }
}

extern "C" void kernel_launch(void* const* d_in, const int* in_sizes, int n_in,
                              void* d_out, int out_size, void* d_ws, size_t ws_size,
                              hipStream_t stream) {
    (void)in_sizes; (void)n_in; (void)out_size; (void)ws_size;
    const float* z   = (const float*)d_in[0];   // [32768,512]
    const float* emb = (const float*)d_in[1];   // [8192,512]
    const float* Wp  = (const float*)d_in[2];   // emb_proj_w [512,512]
    const float* bp  = (const float*)d_in[3];   // emb_proj_b [512]
    const float* Wz  = (const float*)d_in[4];   // z_proj_w [512,512]
    const float* bz  = (const float*)d_in[5];   // z_proj_b [512]
    // d_in[6] = l2_scale: positive scalar, argmin-invariant -> unused

    float* out = (float*)d_out;
    char* ws = (char*)d_ws;
    // ws layout (bytes), total 100,991 KB -- matches R3's proven footprint:
    float* qc            = (float*)(ws + 0);           // 16,777,216
    float* rnorm         = (float*)(ws + 16777216);    //     32,768
    float* tvec          = (float*)(ws + 16809984);    //     32,768
    unsigned short* ehi  = (unsigned short*)(ws + 16842752);   // 8,388,608
    unsigned short* elo  = (unsigned short*)(ws + 25231360);   // 8,388,608
    unsigned short* zhi  = (unsigned short*)(ws + 33619968);   // 33,554,432
    unsigned short* zlo  = (unsigned short*)(ws + 67174400);   // 33,554,432
    unsigned long long* table = (unsigned long long*)(ws + 100728832); // 262,144

    // Phase-overlapped aliases (all dead before their region is overwritten):
    unsigned short* embhi = (unsigned short*)(ws + 33619968);             // 8 MB
    unsigned short* emblo = (unsigned short*)(ws + 33619968 + 8388608);   // 8 MB
    unsigned short* qchi  = (unsigned short*)(ws + 33619968 + 16777216);  // 8 MB
    unsigned short* qclo  = (unsigned short*)(ws + 33619968 + 25165824);  // 8 MB
    unsigned short* wphi  = (unsigned short*)(ws + 67174400);             // 512 KB
    unsigned short* wplo  = (unsigned short*)(ws + 67174400 + 524288);    // 512 KB
    unsigned short* wzthi = (unsigned short*)(ws + 67174400 + 1048576);   // 512 KB
    unsigned short* wztlo = (unsigned short*)(ws + 67174400 + 1572864);   // 512 KB
    float* partials      = (float*)(ws + 33619968);    //    131,072

    hipMemsetAsync(table, 0, (size_t)NQ * 8, stream);

    k_split<<<1024, 256, 0, stream>>>(emb, embhi, emblo, NEMB * DD / 4);
    k_split<<<256, 256, 0, stream>>>(Wp, wphi, wplo, DD * DD / 4);
    k_wtsplit<<<dim3(16, 16), 256, 0, stream>>>(Wz, wzthi, wztlo);

    k_qc_mfma<<<dim3(DD / 128, NEMB / 128), 256, 0, stream>>>(embhi, emblo, wphi, wplo,
                                                              bp, qc, qchi, qclo);
    k_norm<<<NEMB, 256, 0, stream>>>(qc, bz, rnorm, tvec);
    k_e_mfma<<<dim3(DD / 128, NEMB / 128), 256, 0, stream>>>(qchi, qclo, wzthi, wztlo,
                                                             rnorm, ehi, elo);
    k_split<<<4096, 256, 0, stream>>>(z, zhi, zlo, NQ * DD / 4);

    k_scores<<<dim3(NEMB / 256, NQ / 256), 512, 0, stream>>>(zhi, zlo, ehi, elo, tvec, table);
    k_gather<<<NQ, 128, 0, stream>>>(table, qc, z,
                                     out,
                                     partials,
                                     out + (size_t)NQ * DD + 1);
    k_loss<<<1, 1024, 0, stream>>>(partials, out + (size_t)NQ * DD);
}